// Round 4
// baseline (6350.745 us; speedup 1.0000x reference)
//
#include <hip/hip_runtime.h>

#define B_  128
#define T_  256
#define D_  256
#define U_  256
#define TU  768      // 3*U
#define TC  64       // timestep chunk
#define NC  (T_/TC)  // 4 chunks
#define NT  1024     // k2 threads per block

__device__ __forceinline__ float sigm(float x) { return 1.f / (1.f + __expf(-x)); }

// tanh via __expf: tanh(x) = 1 - 2/(e^{2x}+1). ocml tanhf is branchy.
__device__ __forceinline__ float tanh_fast(float x) {
    float e = __expf(2.f * x);
    return 1.f - 2.f / (e + 1.f);
}

__device__ __forceinline__ float rdlane(float v, int l) {
    return __int_as_float(__builtin_amdgcn_readlane(__float_as_int(v), l));
}

// direct cubic B-spline eval: grid cells [g_j, g_j+0.4), g_j = -2.2 + 0.4*j, j=0..10
// nonzero basis m = j-3..j (clipped to 0..7); coeffs at ksw_lds[u*9 + m]
__device__ __forceinline__ float spline_eval(float x, const float* __restrict__ ksw_lds, int u) {
    float xc = (x + 2.2f) * 2.5f;
    float fj = floorf(xc);
    int   j  = (int)fj;
    float tl = xc - fj;
    float t2 = tl * tl, t3 = t2 * tl;
    float om = 1.f - tl;
    const float S = 1.f / 6.f;
    float w0 = om * om * om * S;                            // m = j-3
    float w1 = (3.f * t3 - 6.f * t2 + 4.f) * S;             // m = j-2
    float w2 = (-3.f * t3 + 3.f * t2 + 3.f * tl + 1.f) * S; // m = j-1
    float w3 = t3 * S;                                      // m = j
    bool  v  = (j >= 0) && (j <= 10);
    float r  = 0.f;
#pragma unroll
    for (int k = 0; k < 4; ++k) {
        int   m  = j - 3 + k;
        bool  ok = v && (m >= 0) && (m <= 7);
        int   mc = min(max(m, 0), 7);
        float wk = (k == 0) ? w0 : (k == 1) ? w1 : (k == 2) ? w2 : w3;
        float cf = ksw_lds[u * 9 + mc];
        r += ok ? wk * cf : 0.f;
    }
    return r;
}

// ---------------- K0: zero recurrent state ----------------
__global__ void k0_init(float* __restrict__ wh, float* __restrict__ wc,
                        float* __restrict__ wsub) {
    int i = blockIdx.x * 256 + threadIdx.x;          // grid 128 -> 32768
    wh[i] = 0.f;
    wc[i] = 0.f;
    if (i < 3 * B_) wsub[i] = 0.f;
}

// ---------------- K1: A[b][tl][j] = x[b, t0+tl, :] @ kernel + bias ----------------
__global__ __launch_bounds__(256) void k1_gemm(const float* __restrict__ X,
                                               const float* __restrict__ Km,
                                               const float* __restrict__ bias,
                                               float* __restrict__ A, int t0) {
    __shared__ float Xs[16][68];
    __shared__ float Ks[16][68];
    const int bm  = blockIdx.x * 64;
    const int bn  = blockIdx.y * 64;
    const int tid = threadIdx.x;
    const int ty = tid >> 4, tx = tid & 15;

    const int lr  = tid >> 2;
    const int lk4 = (tid & 3) * 4;
    const int rr  = bm + lr;
    const int b   = rr >> 6;
    const int tl  = rr & 63;
    const float* xrow = X + (size_t)(b * T_ + t0 + tl) * D_;

    const int kr  = tid >> 4;
    const int kn4 = (tid & 15) * 4;

    float acc[4][4] = {};
    for (int kb = 0; kb < 256; kb += 16) {
        float4 xv = *(const float4*)(xrow + kb + lk4);
        Xs[lk4 + 0][lr] = xv.x;
        Xs[lk4 + 1][lr] = xv.y;
        Xs[lk4 + 2][lr] = xv.z;
        Xs[lk4 + 3][lr] = xv.w;
        *(float4*)&Ks[kr][kn4] = *(const float4*)(Km + (size_t)(kb + kr) * TU + bn + kn4);
        __syncthreads();
#pragma unroll
        for (int k = 0; k < 16; ++k) {
            float4 av = *(float4*)&Xs[k][ty * 4];
            float4 bv = *(float4*)&Ks[k][tx * 4];
            acc[0][0] += av.x * bv.x; acc[0][1] += av.x * bv.y; acc[0][2] += av.x * bv.z; acc[0][3] += av.x * bv.w;
            acc[1][0] += av.y * bv.x; acc[1][1] += av.y * bv.y; acc[1][2] += av.y * bv.z; acc[1][3] += av.y * bv.w;
            acc[2][0] += av.z * bv.x; acc[2][1] += av.z * bv.y; acc[2][2] += av.z * bv.z; acc[2][3] += av.z * bv.w;
            acc[3][0] += av.w * bv.x; acc[3][1] += av.w * bv.y; acc[3][2] += av.w * bv.z; acc[3][3] += av.w * bv.w;
        }
        __syncthreads();
    }
    float4 bv = *(const float4*)(bias + bn + tx * 4);
#pragma unroll
    for (int i = 0; i < 4; ++i) {
        float4 o;
        o.x = acc[i][0] + bv.x; o.y = acc[i][1] + bv.y;
        o.z = acc[i][2] + bv.z; o.w = acc[i][3] + bv.w;
        *(float4*)(A + (size_t)(bm + ty * 4 + i) * TU + bn + tx * 4) = o;
    }
}

// ---------------- K2: single-block-per-batch-row recurrence ----------------
// 128 blocks x 1024 threads (16 waves). Block b owns ALL 256 output units for
// batch row b -> h stays in LDS, no cross-block exchange.
//
// ROUND 4 FIX: round 3 compiled at VGPR_Count=64 and SPILLED Rf to scratch
// (FETCH_SIZE 25 MB -> 1.7 GB, the whole regression). Pin the register budget:
// 16 waves/block at 1 block/CU = 4 waves/SIMD -> amdgpu_waves_per_eu(4,4)
// gives 2048/4 = 512 regs/wave combined VGPR+AGPR budget; Rf (192) + working
// set (~64) fits with 2x margin. Keep-alive asm defeats remat-into-loop.
__global__ __launch_bounds__(NT)
__attribute__((amdgpu_waves_per_eu(4, 4)))
void k2_rec(const float* __restrict__ A,
            const float* __restrict__ X,
            const float* __restrict__ R,
            const float* __restrict__ stk,
            const float* __restrict__ strk,
            const float* __restrict__ aggw,
            const float* __restrict__ aggb,
            const float* __restrict__ kbw,
            const float* __restrict__ ksw,
            float* __restrict__ out,
            float* __restrict__ ws_h,
            float* __restrict__ ws_c,
            float* __restrict__ ws_sub,
            int t0) {
    __shared__ float hs[256];
    __shared__ float xs[256];
    __shared__ float zred[16][64][3];
    __shared__ float kred[768];
    __shared__ float so_l[3];
    __shared__ float subs[3];
    __shared__ float st2[6];
    __shared__ float hhist[TC][256];        // 64 KB h history -> epilogue bulk write
    __shared__ float ksw_lds[768 * 9];      // ~27.6 KB, *9 stride breaks bank conflicts

    const int tid  = threadIdx.x;
    const int lane = tid & 63;
    const int w    = tid >> 6;              // 0..15
    const int p    = w & 3;                 // h-segment
    const int c    = ((w >> 2) << 6) | lane; // 0..255 = output unit ui
    const int b    = blockIdx.x;
    const bool pstate = (p == 0);           // waves 0,4,8,12 hold gate state

    // ---- stationary R fragment: Rf[g][uu] = R[p*64+uu][g*256 + c] ----
    float Rf[3][64];
#pragma unroll
    for (int g = 0; g < 3; ++g)
#pragma unroll
        for (int uu = 0; uu < 64; ++uu)
            Rf[g][uu] = R[(size_t)(p * 64 + uu) * TU + g * 256 + c];

    // keep-alive: values become opaque -> RA cannot rematerialize the R loads
    // (or spill-reload) inside the timestep loop. It must keep them in the
    // unified VGPR/AGPR file (budget 512/wave via waves_per_eu(4,4)).
#pragma unroll
    for (int g = 0; g < 3; ++g)
#pragma unroll
        for (int uu = 0; uu < 64; ++uu)
            asm volatile("" : "+v"(Rf[g][uu]));

    // ---- KAN stationary weights: thread tid<768 owns unit u=tid (s0 = tid>>8, d0 = tid&255) ----
    const int s0 = tid >> 8;
    const int d0 = tid & 255;
    float skx0 = 0.f, skh0 = 0.f, bw0 = 0.f;
    if (tid < 768) {
        skx0 = strk[s0 * 512 + d0];
        skh0 = strk[s0 * 512 + 256 + d0];
        bw0  = kbw[tid];
    }

    const float aw0 = aggw[c], aw1 = aggw[256 + c], aw2 = aggw[512 + c], ab = aggb[c];
    float c_reg = pstate ? ws_c[b * 256 + c] : 0.f;

    for (int i = tid; i < 768 * 8; i += NT) ksw_lds[(i >> 3) * 9 + (i & 7)] = ksw[i];
    if (tid < 256) hs[tid] = ws_h[b * 256 + tid];
    if (tid < 256) xs[tid] = X[((size_t)b * T_ + t0) * D_ + tid];
    if (tid < 3)   subs[tid] = ws_sub[b * 3 + tid];
    if (tid < 6)   st2[tid] = stk[tid];

    // prologue A(t0) load (held in regs by pstate waves)
    float az0 = 0.f, az1 = 0.f, az2 = 0.f;
    if (pstate) {
        const float* Ap = A + ((size_t)b * TC) * TU + c;
        az0 = Ap[0]; az1 = Ap[256]; az2 = Ap[512];
    }
    __syncthreads();

    for (int tl = 0; tl < TC; ++tl) {
        const int t = t0 + tl;

        // ---- phase A: issue next-step A/X loads, KAN eval, GEMV ----
        float an0 = 0.f, an1 = 0.f, an2 = 0.f;
        if (pstate && tl + 1 < TC) {
            const float* Ap = A + ((size_t)b * TC + tl + 1) * TU + c;
            an0 = Ap[0]; an1 = Ap[256]; an2 = Ap[512];
        }
        float xv = 0.f;
        if (tid >= 768) {                    // waves 12-15 prefetch x_{t+1}
            int tn = (t + 1 < T_) ? t + 1 : t;
            xv = X[((size_t)b * T_ + tn) * D_ + (tid - 768)];
        }
        if (tid < 768) {                     // KAN eval (reads xs(t), subs)
            float a0 = xs[d0] * skx0 + subs[s0] * skh0;
            kred[tid] = a0 * sigm(a0) * bw0 + spline_eval(a0, ksw_lds, tid);
        }
        {                                    // GEMV partials, R stationary
            float hreg = hs[p * 64 + lane];
            float a0 = 0.f, a1 = 0.f, a2 = 0.f;
#pragma unroll
            for (int uu = 0; uu < 64; ++uu) {
                float hu = rdlane(hreg, uu);
                a0 = fmaf(hu, Rf[0][uu], a0);
                a1 = fmaf(hu, Rf[1][uu], a1);
                a2 = fmaf(hu, Rf[2][uu], a2);
            }
            zred[w][lane][0] = a0;
            zred[w][lane][1] = a1;
            zred[w][lane][2] = a2;
        }
        __syncthreads();   // B1: kred+zred visible; A/X loads drained (hidden by work)

        // ---- phase B: KAN reduce (waves 0-2), stage xs(t+1) (waves 12-15) ----
        if (w < 3) {
            float v = kred[w * 256 + lane] + kred[w * 256 + 64 + lane]
                    + kred[w * 256 + 128 + lane] + kred[w * 256 + 192 + lane];
#pragma unroll
            for (int m = 32; m > 0; m >>= 1) v += __shfl_xor(v, m, 64);
            if (lane == 0) {
                so_l[w] = v;
                subs[w] = st2[w * 2] * v + st2[w * 2 + 1] * subs[w];
            }
        }
        if (tid >= 768) xs[tid - 768] = xv;
        __syncthreads();   // B2: so_l/subs/xs(t+1) visible

        // ---- phase C: gates + state update (pstate waves only) ----
        if (pstate) {
            float z0 = az0, z1 = az1, z2 = az2;
#pragma unroll
            for (int q = 0; q < 4; ++q) {
                z0 += zred[w + q][lane][0];
                z1 += zred[w + q][lane][1];
                z2 += zred[w + q][lane][2];
            }
            float ig = sigm(z0);
            float fg = sigm(z1);
            c_reg = fg * c_reg + ig * tanh_fast(z2);
            float og = sigm(so_l[0] * aw0 + so_l[1] * aw1 + so_l[2] * aw2 + ab);
            float hn = og * tanh_fast(c_reg);
            hs[c] = hn;
            hhist[tl][c] = hn;
            if (tl == TC - 1) {
                ws_h[b * 256 + c] = hn;
                ws_c[b * 256 + c] = c_reg;
            }
            az0 = an0; az1 = an1; az2 = an2;
        }
        __syncthreads();   // B3: hs(t) visible for next GEMV
    }

    // ---- epilogue: bulk out-write from LDS history (coalesced) ----
    for (int i = tid; i < TC * 256; i += NT)
        out[((size_t)b * T_ + t0 + (i >> 8)) * U_ + (i & 255)] = hhist[i >> 8][i & 255];
    if (tid < 3) ws_sub[b * 3 + tid] = subs[tid];
}

extern "C" void kernel_launch(void* const* d_in, const int* in_sizes, int n_in,
                              void* d_out, int out_size, void* d_ws, size_t ws_size,
                              hipStream_t stream) {
    const float* x    = (const float*)d_in[0];
    const float* Kmat = (const float*)d_in[1];
    const float* R    = (const float*)d_in[2];
    const float* bias = (const float*)d_in[3];
    const float* stk  = (const float*)d_in[4];
    const float* strk = (const float*)d_in[5];
    const float* aggw = (const float*)d_in[6];
    const float* aggb = (const float*)d_in[7];
    const float* kbw  = (const float*)d_in[8];
    const float* ksw  = (const float*)d_in[9];
    float* out = (float*)d_out;

    float* ws   = (float*)d_ws;
    float* A    = ws;                             // 6,291,456 floats (24 MB)
    float* wh   = A + (size_t)B_ * TC * TU;       // 32768
    float* wc   = wh + B_ * U_;                   // 32768
    float* wsub = wc + B_ * U_;                   // 384 (pad to 512)

    k0_init<<<dim3(B_), dim3(256), 0, stream>>>(wh, wc, wsub);
    for (int ci = 0; ci < NC; ++ci) {
        k1_gemm<<<dim3((B_ * TC) / 64, TU / 64), dim3(256), 0, stream>>>(x, Kmat, bias, A, ci * TC);
        k2_rec<<<dim3(B_), dim3(NT), 0, stream>>>(A, x, R, stk, strk, aggw, aggb, kbw, ksw,
                                                  out, wh, wc, wsub, ci * TC);
    }
}

// Round 5
// 1192.262 us; speedup vs baseline: 5.3266x; 5.3266x over previous
//
#include <hip/hip_runtime.h>

#define B_  128
#define T_  256
#define D_  256
#define U_  256
#define TU  768      // 3*U
#define TC  64       // timestep chunk
#define NC  (T_/TC)  // 4 chunks

__device__ __forceinline__ float sigm(float x) { return 1.f / (1.f + __expf(-x)); }

// tanh via __expf: tanh(x) = 1 - 2/(e^{2x}+1). ocml tanhf is branchy.
// (absmax unchanged across R2-R4 with this: 0.00390625)
__device__ __forceinline__ float tanh_fast(float x) {
    float e = __expf(2.f * x);
    return 1.f - 2.f / (e + 1.f);
}

__device__ __forceinline__ float rdlane(float v, int l) {
    return __int_as_float(__builtin_amdgcn_readlane(__float_as_int(v), l));
}

// direct cubic B-spline eval: grid cells [g_j, g_j+0.4), g_j = -2.2 + 0.4*j, j=0..10
// nonzero basis m = j-3..j (clipped to 0..7); coeffs at ksw_lds[u*9 + m]
__device__ __forceinline__ float spline_eval(float x, const float* __restrict__ ksw_lds, int u) {
    float xc = (x + 2.2f) * 2.5f;
    float fj = floorf(xc);
    int   j  = (int)fj;
    float tl = xc - fj;
    float t2 = tl * tl, t3 = t2 * tl;
    float om = 1.f - tl;
    const float S = 1.f / 6.f;
    float w0 = om * om * om * S;                            // m = j-3
    float w1 = (3.f * t3 - 6.f * t2 + 4.f) * S;             // m = j-2
    float w2 = (-3.f * t3 + 3.f * t2 + 3.f * tl + 1.f) * S; // m = j-1
    float w3 = t3 * S;                                      // m = j
    bool  v  = (j >= 0) && (j <= 10);
    float r  = 0.f;
#pragma unroll
    for (int k = 0; k < 4; ++k) {
        int   m  = j - 3 + k;
        bool  ok = v && (m >= 0) && (m <= 7);
        int   mc = min(max(m, 0), 7);
        float wk = (k == 0) ? w0 : (k == 1) ? w1 : (k == 2) ? w2 : w3;
        float cf = ksw_lds[u * 9 + mc];
        r += ok ? wk * cf : 0.f;
    }
    return r;
}

// ---------------- K0: zero recurrent state + init exchange flags ----------------
__global__ void k0_init(float* __restrict__ wh, float* __restrict__ wc,
                        float* __restrict__ wsub, int* __restrict__ flags) {
    int i = blockIdx.x * 256 + threadIdx.x;          // grid 128 -> 32768
    wh[i] = 0.f;
    wc[i] = 0.f;
    if (i < 3 * B_) wsub[i] = 0.f;
    if (i < 2 * B_) flags[i] = -1;
}

// ---------------- K1: A[b][tl][j] = x[b, t0+tl, :] @ kernel + bias ----------------
__global__ __launch_bounds__(256) void k1_gemm(const float* __restrict__ X,
                                               const float* __restrict__ Km,
                                               const float* __restrict__ bias,
                                               float* __restrict__ A, int t0) {
    __shared__ float Xs[16][68];
    __shared__ float Ks[16][68];
    const int bm  = blockIdx.x * 64;
    const int bn  = blockIdx.y * 64;
    const int tid = threadIdx.x;
    const int ty = tid >> 4, tx = tid & 15;

    const int lr  = tid >> 2;
    const int lk4 = (tid & 3) * 4;
    const int rr  = bm + lr;
    const int b   = rr >> 6;
    const int tl  = rr & 63;
    const float* xrow = X + (size_t)(b * T_ + t0 + tl) * D_;

    const int kr  = tid >> 4;
    const int kn4 = (tid & 15) * 4;

    float acc[4][4] = {};
    for (int kb = 0; kb < 256; kb += 16) {
        float4 xv = *(const float4*)(xrow + kb + lk4);
        Xs[lk4 + 0][lr] = xv.x;
        Xs[lk4 + 1][lr] = xv.y;
        Xs[lk4 + 2][lr] = xv.z;
        Xs[lk4 + 3][lr] = xv.w;
        *(float4*)&Ks[kr][kn4] = *(const float4*)(Km + (size_t)(kb + kr) * TU + bn + kn4);
        __syncthreads();
#pragma unroll
        for (int k = 0; k < 16; ++k) {
            float4 av = *(float4*)&Xs[k][ty * 4];
            float4 bv = *(float4*)&Ks[k][tx * 4];
            acc[0][0] += av.x * bv.x; acc[0][1] += av.x * bv.y; acc[0][2] += av.x * bv.z; acc[0][3] += av.x * bv.w;
            acc[1][0] += av.y * bv.x; acc[1][1] += av.y * bv.y; acc[1][2] += av.y * bv.z; acc[1][3] += av.y * bv.w;
            acc[2][0] += av.z * bv.x; acc[2][1] += av.z * bv.y; acc[2][2] += av.z * bv.z; acc[2][3] += av.z * bv.w;
            acc[3][0] += av.w * bv.x; acc[3][1] += av.w * bv.y; acc[3][2] += av.w * bv.z; acc[3][3] += av.w * bv.w;
        }
        __syncthreads();
    }
    float4 bv = *(const float4*)(bias + bn + tx * 4);
#pragma unroll
    for (int i = 0; i < 4; ++i) {
        float4 o;
        o.x = acc[i][0] + bv.x; o.y = acc[i][1] + bv.y;
        o.z = acc[i][2] + bv.z; o.w = acc[i][3] + bv.w;
        *(float4*)(A + (size_t)(bm + ty * 4 + i) * TU + bn + tx * 4) = o;
    }
}

// ---------------- K2: pair-split recurrence, R stationary in regs ----------------
// Structure = proven R0 baseline (520 us/dispatch): 256 blocks x 512 thr, block
// (b = idx&127, r = idx>>7) owns units r*128..r*128+127; Rf[3][64] stationary in
// the unified VGPR/AGPR file (512 thr x 256 regs = 512 KB = full CU RF; this is
// the ONLY feasible fp32 tiling -- R4 proved 1024-thr blocks must spill).
//
// ROUND 5 CHANGE (one mechanism): exchange via fine-grain L3 coherence.
// R0 used agent-scope acquire PER POLL (buffer_inv = L2 invalidate each
// iteration) + agent-scope release per step (buffer_wbl2 = full dirty-L2
// writeback). Now: SYSTEM-scope RELAXED atomics -> global_load/store sc0 sc1
// (read-through/write-through at Infinity Cache, per-access, NO cache
// maintenance). Ordering: __syncthreads lowering drains vmcnt(0) per wave
// before s_barrier, so after sync5 all xh write-through stores are in L3;
// tid0 then publishes the flag. Reader: relaxed poll -> compiler barrier ->
// relaxed xh read (L3 is the common coherence point; no staleness possible).
// Also: out-store moved out of the loop (hhist in LDS, epilogue bulk write)
// so the sync5 drain no longer waits on an HBM store.
__global__ __launch_bounds__(512, 2)
void k2_rec(const float* __restrict__ A,
            const float* __restrict__ X,
            const float* __restrict__ R,
            const float* __restrict__ stk,
            const float* __restrict__ strk,
            const float* __restrict__ aggw,
            const float* __restrict__ aggb,
            const float* __restrict__ kbw,
            const float* __restrict__ ksw,
            float* __restrict__ out,
            float* __restrict__ ws_h,
            float* __restrict__ ws_c,
            float* __restrict__ ws_sub,
            float* __restrict__ xh,    // [B][2][256]
            int* __restrict__ flags,   // [B][2]
            int t0) {
    __shared__ float hs[256];
    __shared__ float xs[256];
    __shared__ float zred[8][64][3];
    __shared__ float kred[768];
    __shared__ float so_l[3];
    __shared__ float subs[3];
    __shared__ float st2[6];
    __shared__ float hhist[TC][128];        // 32 KB h history -> epilogue bulk write
    __shared__ float ksw_lds[768 * 9];

    const int tid  = threadIdx.x;
    const int lane = tid & 63;
    const int w    = tid >> 6;
    const int p    = w & 3;
    const int c    = ((w >> 2) << 6) | lane;   // 0..127
    const int b    = blockIdx.x & 127;
    const int r    = blockIdx.x >> 7;
    const int ui   = r * 128 + c;              // global output-unit index
    const bool pstate = (p == 0);              // waves 0 and 4 hold gate state

    // ---- stationary R fragment (lives in unified VGPR/AGPR file) ----
    float Rf[3][64];
#pragma unroll
    for (int g = 0; g < 3; ++g)
#pragma unroll
        for (int uu = 0; uu < 64; ++uu)
            Rf[g][uu] = R[(size_t)(p * 64 + uu) * TU + g * 256 + ui];

    // ---- KAN stationary weights (unit u0 = tid; u1 = tid+512 for tid<256) ----
    const int s0 = tid >> 8, d0 = tid & 255;
    const float skx0 = strk[s0 * 512 + d0];
    const float skh0 = strk[s0 * 512 + 256 + d0];
    const float bw0  = kbw[tid];
    float skx1 = 0.f, skh1 = 0.f, bw1 = 0.f;
    if (tid < 256) {
        skx1 = strk[2 * 512 + tid];
        skh1 = strk[2 * 512 + 256 + tid];
        bw1  = kbw[512 + tid];
    }

    const float aw0 = aggw[ui], aw1 = aggw[256 + ui], aw2 = aggw[512 + ui], ab = aggb[ui];
    float c_reg = ws_c[b * 256 + ui];

    for (int i = tid; i < 768 * 8; i += 512) ksw_lds[(i >> 3) * 9 + (i & 7)] = ksw[i];
    if (tid < 256) hs[tid] = ws_h[b * 256 + tid];
    if (tid < 3)   subs[tid] = ws_sub[b * 3 + tid];
    if (tid < 6)   st2[tid] = stk[tid];

    int* pflag = &flags[b * 2 + (1 - r)];

    for (int tl = 0; tl < TC; ++tl) {
        const int t = t0 + tl;

        // ---- phase1: stage x_t, prefetch A ----
        float az0 = 0.f, az1 = 0.f, az2 = 0.f;
        if (pstate) {
            const float* Ap = A + ((size_t)b * TC + tl) * TU + ui;
            az0 = Ap[0]; az1 = Ap[256]; az2 = Ap[512];
        }
        if (tid < 256) xs[tid] = X[((size_t)b * T_ + t) * D_ + tid];
        __syncthreads();   // sync1: xs (and init LDS on first iter) visible

        // ---- phase2: KAN evals (no h dependency) + fetch partner h-half ----
        {
            float a0 = xs[d0] * skx0 + subs[s0] * skh0;
            kred[tid] = a0 * sigm(a0) * bw0 + spline_eval(a0, ksw_lds, tid);
        }
        if (tid < 256) {
            float a1 = xs[tid] * skx1 + subs[2] * skh1;
            kred[512 + tid] = a1 * sigm(a1) * bw1 + spline_eval(a1, ksw_lds, 512 + tid);
        }
        if (tl > 0 && tid < 128) {
            const int uidx = (1 - r) * 128 + tid;
            // relaxed system-scope poll: global_load sc0 sc1 (L3 read-through),
            // NO buffer_inv per iteration (that was R0's per-poll cost).
            while (__hip_atomic_load(pflag, __ATOMIC_RELAXED, __HIP_MEMORY_SCOPE_SYSTEM) < t - 1) {}
            asm volatile("" ::: "memory");   // compiler ordering only; HW ordered via L3
            hs[uidx] = __hip_atomic_load(&xh[((size_t)b * 2 + ((t - 1) & 1)) * 256 + uidx],
                                         __ATOMIC_RELAXED, __HIP_MEMORY_SCOPE_SYSTEM);
        }
        __syncthreads();   // sync2: kred + full hs ready

        // ---- phase3: GEMV partials, R stationary ----
        {
            float hreg = hs[p * 64 + lane];
            float a0 = 0.f, a1 = 0.f, a2 = 0.f;
#pragma unroll
            for (int uu = 0; uu < 64; ++uu) {
                float hu = rdlane(hreg, uu);
                a0 = fmaf(hu, Rf[0][uu], a0);
                a1 = fmaf(hu, Rf[1][uu], a1);
                a2 = fmaf(hu, Rf[2][uu], a2);
            }
            zred[w][lane][0] = a0;
            zred[w][lane][1] = a1;
            zred[w][lane][2] = a2;
        }
        __syncthreads();   // sync3

        // ---- phase4: KAN reduce (one wave per s) ----
        if (w < 3) {
            float v = kred[w * 256 + lane] + kred[w * 256 + 64 + lane]
                    + kred[w * 256 + 128 + lane] + kred[w * 256 + 192 + lane];
#pragma unroll
            for (int m = 32; m > 0; m >>= 1) v += __shfl_xor(v, m, 64);
            if (lane == 0) {
                so_l[w] = v;
                subs[w] = st2[w * 2] * v + st2[w * 2 + 1] * subs[w];
            }
        }
        __syncthreads();   // sync4

        // ---- phase5: gates + state update + publish (write-through stores) ----
        if (pstate) {
            float z0 = az0, z1 = az1, z2 = az2;
#pragma unroll
            for (int q = 0; q < 4; ++q) {
                z0 += zred[w + q][lane][0];
                z1 += zred[w + q][lane][1];
                z2 += zred[w + q][lane][2];
            }
            float ig = sigm(z0);
            float fg = sigm(z1);
            c_reg = fg * c_reg + ig * tanh_fast(z2);
            float og = sigm(so_l[0] * aw0 + so_l[1] * aw1 + so_l[2] * aw2 + ab);
            float hn = og * tanh_fast(c_reg);
            hs[ui] = hn;
            hhist[tl][c] = hn;
            if (tl < TC - 1) {
                // system-scope relaxed store: global_store sc0 sc1, write-through
                // to L3 (no wbL2 needed for partner visibility).
                __hip_atomic_store(&xh[((size_t)b * 2 + (t & 1)) * 256 + ui], hn,
                                   __ATOMIC_RELAXED, __HIP_MEMORY_SCOPE_SYSTEM);
            } else {
                ws_h[b * 256 + ui] = hn;
                ws_c[b * 256 + ui] = c_reg;
            }
        }
        __syncthreads();   // sync5: each wave drains vmcnt(0) before s_barrier
                           //        -> all xh stores are IN L3 past this point
        if (tid == 0 && tl < TC - 1) {
            asm volatile("s_waitcnt vmcnt(0)" ::: "memory");  // belt-and-braces, free
            __hip_atomic_store(&flags[b * 2 + r], t,
                               __ATOMIC_RELAXED, __HIP_MEMORY_SCOPE_SYSTEM);
        }
    }

    // ---- epilogue: bulk out-write from LDS history (coalesced, off serial path) ----
    for (int i = tid; i < TC * 128; i += 512) {
        int tl = i >> 7, cc = i & 127;
        out[((size_t)b * T_ + t0 + tl) * U_ + r * 128 + cc] = hhist[tl][cc];
    }
    if (tid < 3) ws_sub[b * 3 + tid] = subs[tid];
}

extern "C" void kernel_launch(void* const* d_in, const int* in_sizes, int n_in,
                              void* d_out, int out_size, void* d_ws, size_t ws_size,
                              hipStream_t stream) {
    const float* x    = (const float*)d_in[0];
    const float* Kmat = (const float*)d_in[1];
    const float* R    = (const float*)d_in[2];
    const float* bias = (const float*)d_in[3];
    const float* stk  = (const float*)d_in[4];
    const float* strk = (const float*)d_in[5];
    const float* aggw = (const float*)d_in[6];
    const float* aggb = (const float*)d_in[7];
    const float* kbw  = (const float*)d_in[8];
    const float* ksw  = (const float*)d_in[9];
    float* out = (float*)d_out;

    float* ws   = (float*)d_ws;
    float* A    = ws;                             // 6,291,456 floats (24 MB)
    float* wh   = A + (size_t)B_ * TC * TU;       // 32768
    float* wc   = wh + B_ * U_;                   // 32768
    float* wsub = wc + B_ * U_;                   // 384 (pad to 512)
    float* xh   = wsub + 512;                     // B*2*256 = 65536
    int*   flg  = (int*)(xh + (size_t)B_ * 2 * 256);  // 256 ints

    k0_init<<<dim3(B_), dim3(256), 0, stream>>>(wh, wc, wsub, flg);
    for (int ci = 0; ci < NC; ++ci) {
        k1_gemm<<<dim3((B_ * TC) / 64, TU / 64), dim3(256), 0, stream>>>(x, Kmat, bias, A, ci * TC);
        k2_rec<<<dim3(2 * B_), dim3(512), 0, stream>>>(A, x, R, stk, strk, aggw, aggb, kbw, ksw,
                                                       out, wh, wc, wsub, xh, flg, ci * TC);
    }
}

// Round 6
// 1092.851 us; speedup vs baseline: 5.8112x; 1.0910x over previous
//
#include <hip/hip_runtime.h>

#define B_  128
#define T_  256
#define D_  256
#define U_  256
#define TU  768      // 3*U
#define TC  64       // timestep chunk
#define NC  (T_/TC)  // 4 chunks

__device__ __forceinline__ float sigm(float x) { return 1.f / (1.f + __expf(-x)); }

// tanh via __expf: tanh(x) = 1 - 2/(e^{2x}+1). (absmax unchanged since R2)
__device__ __forceinline__ float tanh_fast(float x) {
    float e = __expf(2.f * x);
    return 1.f - 2.f / (e + 1.f);
}

__device__ __forceinline__ float rdlane(float v, int l) {
    return __int_as_float(__builtin_amdgcn_readlane(__float_as_int(v), l));
}

// direct cubic B-spline eval: grid cells [g_j, g_j+0.4), g_j = -2.2 + 0.4*j, j=0..10
// nonzero basis m = j-3..j (clipped to 0..7); coeffs at ksw_lds[u*9 + m]
__device__ __forceinline__ float spline_eval(float x, const float* __restrict__ ksw_lds, int u) {
    float xc = (x + 2.2f) * 2.5f;
    float fj = floorf(xc);
    int   j  = (int)fj;
    float tl = xc - fj;
    float t2 = tl * tl, t3 = t2 * tl;
    float om = 1.f - tl;
    const float S = 1.f / 6.f;
    float w0 = om * om * om * S;                            // m = j-3
    float w1 = (3.f * t3 - 6.f * t2 + 4.f) * S;             // m = j-2
    float w2 = (-3.f * t3 + 3.f * t2 + 3.f * tl + 1.f) * S; // m = j-1
    float w3 = t3 * S;                                      // m = j
    bool  v  = (j >= 0) && (j <= 10);
    float r  = 0.f;
#pragma unroll
    for (int k = 0; k < 4; ++k) {
        int   m  = j - 3 + k;
        bool  ok = v && (m >= 0) && (m <= 7);
        int   mc = min(max(m, 0), 7);
        float wk = (k == 0) ? w0 : (k == 1) ? w1 : (k == 2) ? w2 : w3;
        float cf = ksw_lds[u * 9 + mc];
        r += ok ? wk * cf : 0.f;
    }
    return r;
}

// ---------------- K0: zero recurrent state + init exchange flags ----------------
__global__ void k0_init(float* __restrict__ wh, float* __restrict__ wc,
                        float* __restrict__ wsub, int* __restrict__ flags) {
    int i = blockIdx.x * 256 + threadIdx.x;          // grid 128 -> 32768
    wh[i] = 0.f;
    wc[i] = 0.f;
    if (i < 3 * B_) wsub[i] = 0.f;
    if (i < 4 * B_) flags[i] = -1;                   // [B][2 r][2 half]
}

// ---------------- K1: A[b][tl][j] = x[b, t0+tl, :] @ kernel + bias ----------------
__global__ __launch_bounds__(256) void k1_gemm(const float* __restrict__ X,
                                               const float* __restrict__ Km,
                                               const float* __restrict__ bias,
                                               float* __restrict__ A, int t0) {
    __shared__ float Xs[16][68];
    __shared__ float Ks[16][68];
    const int bm  = blockIdx.x * 64;
    const int bn  = blockIdx.y * 64;
    const int tid = threadIdx.x;
    const int ty = tid >> 4, tx = tid & 15;

    const int lr  = tid >> 2;
    const int lk4 = (tid & 3) * 4;
    const int rr  = bm + lr;
    const int b   = rr >> 6;
    const int tl  = rr & 63;
    const float* xrow = X + (size_t)(b * T_ + t0 + tl) * D_;

    const int kr  = tid >> 4;
    const int kn4 = (tid & 15) * 4;

    float acc[4][4] = {};
    for (int kb = 0; kb < 256; kb += 16) {
        float4 xv = *(const float4*)(xrow + kb + lk4);
        Xs[lk4 + 0][lr] = xv.x;
        Xs[lk4 + 1][lr] = xv.y;
        Xs[lk4 + 2][lr] = xv.z;
        Xs[lk4 + 3][lr] = xv.w;
        *(float4*)&Ks[kr][kn4] = *(const float4*)(Km + (size_t)(kb + kr) * TU + bn + kn4);
        __syncthreads();
#pragma unroll
        for (int k = 0; k < 16; ++k) {
            float4 av = *(float4*)&Xs[k][ty * 4];
            float4 bv = *(float4*)&Ks[k][tx * 4];
            acc[0][0] += av.x * bv.x; acc[0][1] += av.x * bv.y; acc[0][2] += av.x * bv.z; acc[0][3] += av.x * bv.w;
            acc[1][0] += av.y * bv.x; acc[1][1] += av.y * bv.y; acc[1][2] += av.y * bv.z; acc[1][3] += av.y * bv.w;
            acc[2][0] += av.z * bv.x; acc[2][1] += av.z * bv.y; acc[2][2] += av.z * bv.z; acc[2][3] += av.z * bv.w;
            acc[3][0] += av.w * bv.x; acc[3][1] += av.w * bv.y; acc[3][2] += av.w * bv.z; acc[3][3] += av.w * bv.w;
        }
        __syncthreads();
    }
    float4 bv = *(const float4*)(bias + bn + tx * 4);
#pragma unroll
    for (int i = 0; i < 4; ++i) {
        float4 o;
        o.x = acc[i][0] + bv.x; o.y = acc[i][1] + bv.y;
        o.z = acc[i][2] + bv.z; o.w = acc[i][3] + bv.w;
        *(float4*)(A + (size_t)(bm + ty * 4 + i) * TU + bn + tx * 4) = o;
    }
}

// ---------------- K2: pair-split recurrence, R stationary in regs ----------------
// R5 structure (verified 238 us) + round-6 schedule surgery:
//  * 3 barriers/step instead of 5 (phase DAG: {KAN+poll} -> {GEMV+KANred+xstage}
//    -> {gates+publish}).
//  * A(t+1)/x(t+1) loads issued at TOP of phase A; drained for free at syncA
//    (covered by KAN VALU work); consumed from registers next step. Removes the
//    exposed vmcnt(0) load drain R5 paid at sync1 every step.
//  * EARLY per-wave publish: pstate wave stores its 64 xh values (relaxed system,
//    L3 write-through), one wave-level s_waitcnt vmcnt(0) (only its own stores
//    outstanding), lane0 stores its half-flag -- partner unblocked before our
//    block-wide barrier. R2's version of this lost only because each publish was
//    an agent-RELEASE (full wbl2); relaxed+waitcnt is ~free.
//  * polling moved to waves 6,7 (off the pstate critical path).
__global__ __launch_bounds__(512, 2)
void k2_rec(const float* __restrict__ A,
            const float* __restrict__ X,
            const float* __restrict__ R,
            const float* __restrict__ stk,
            const float* __restrict__ strk,
            const float* __restrict__ aggw,
            const float* __restrict__ aggb,
            const float* __restrict__ kbw,
            const float* __restrict__ ksw,
            float* __restrict__ out,
            float* __restrict__ ws_h,
            float* __restrict__ ws_c,
            float* __restrict__ ws_sub,
            float* __restrict__ xh,    // [B][2][256]
            int* __restrict__ flags,   // [B][2 r][2 half]
            int t0) {
    __shared__ float hs[256];
    __shared__ float xs[256];
    __shared__ float zred[8][64][3];
    __shared__ float kred[768];
    __shared__ float so_l[3];
    __shared__ float subs[3];
    __shared__ float st2[6];
    __shared__ float hhist[TC][128];        // 32 KB h history -> epilogue bulk write
    __shared__ float ksw_lds[768 * 9];

    const int tid  = threadIdx.x;
    const int lane = tid & 63;
    const int w    = tid >> 6;
    const int p    = w & 3;
    const int c    = ((w >> 2) << 6) | lane;   // 0..127
    const int b    = blockIdx.x & 127;
    const int r    = blockIdx.x >> 7;
    const int ui   = r * 128 + c;              // global output-unit index
    const bool pstate = (p == 0);              // waves 0 and 4 hold gate state

    // ---- stationary R fragment (lives in unified VGPR/AGPR file) ----
    float Rf[3][64];
#pragma unroll
    for (int g = 0; g < 3; ++g)
#pragma unroll
        for (int uu = 0; uu < 64; ++uu)
            Rf[g][uu] = R[(size_t)(p * 64 + uu) * TU + g * 256 + ui];

    // ---- KAN stationary weights (unit u0 = tid; u1 = tid+512 for tid<256) ----
    const int s0 = tid >> 8, d0 = tid & 255;
    const float skx0 = strk[s0 * 512 + d0];
    const float skh0 = strk[s0 * 512 + 256 + d0];
    const float bw0  = kbw[tid];
    float skx1 = 0.f, skh1 = 0.f, bw1 = 0.f;
    if (tid < 256) {
        skx1 = strk[2 * 512 + tid];
        skh1 = strk[2 * 512 + 256 + tid];
        bw1  = kbw[512 + tid];
    }

    const float aw0 = aggw[ui], aw1 = aggw[256 + ui], aw2 = aggw[512 + ui], ab = aggb[ui];
    float c_reg = ws_c[b * 256 + ui];

    for (int i = tid; i < 768 * 8; i += 512) ksw_lds[(i >> 3) * 9 + (i & 7)] = ksw[i];
    if (tid < 256) hs[tid] = ws_h[b * 256 + tid];
    if (tid < 256) xs[tid] = X[((size_t)b * T_ + t0) * D_ + tid];
    if (tid < 3)   subs[tid] = ws_sub[b * 3 + tid];
    if (tid < 6)   st2[tid] = stk[tid];

    // poll duty: waves 6,7 (tid>=384); wave 6 -> partner half 0, wave 7 -> half 1
    int* pflag = &flags[(b * 2 + (1 - r)) * 2 + ((tid >> 6) & 1)];
    // x-prefetch duty: waves 2-5 (tid 128..383) cover x indices 0..255
    const bool xduty = (tid >= 128 && tid < 384);
    const int  xi    = tid - 128;

    // prologue: A(t0) into az (pstate)
    float az0 = 0.f, az1 = 0.f, az2 = 0.f;
    if (pstate) {
        const float* Ap = A + ((size_t)b * TC) * TU + ui;
        az0 = Ap[0]; az1 = Ap[256]; az2 = Ap[512];
    }
    __syncthreads();   // prologue LDS (xs(t0), hs, subs, st2, ksw_lds) visible

    for (int tl = 0; tl < TC; ++tl) {
        const int t = t0 + tl;

        // ======== phase A: issue prefetches, KAN eval, poll+fetch partner h ========
        float an0 = 0.f, an1 = 0.f, an2 = 0.f;
        if (pstate && tl + 1 < TC) {               // A(t+1) issue (drains at syncA)
            const float* Ap = A + ((size_t)b * TC + tl + 1) * TU + ui;
            an0 = Ap[0]; an1 = Ap[256]; an2 = Ap[512];
        }
        float xv = 0.f;
        if (xduty) {                               // x(t+1) issue (drains at syncA)
            int tn = (t + 1 < T_) ? t + 1 : t;
            xv = X[((size_t)b * T_ + tn) * D_ + xi];
        }
        {                                          // KAN eval u0 (reads xs(t), subs)
            float a0 = xs[d0] * skx0 + subs[s0] * skh0;
            kred[tid] = a0 * sigm(a0) * bw0 + spline_eval(a0, ksw_lds, tid);
        }
        if (tid < 256) {                           // KAN eval u1
            float a1 = xs[tid] * skx1 + subs[2] * skh1;
            kred[512 + tid] = a1 * sigm(a1) * bw1 + spline_eval(a1, ksw_lds, 512 + tid);
        }
        if (tl > 0 && tid >= 384) {                // waves 6,7: poll + fetch partner h
            const int uidx = (1 - r) * 128 + (tid - 384);
            while (__hip_atomic_load(pflag, __ATOMIC_RELAXED, __HIP_MEMORY_SCOPE_SYSTEM) < t - 1) {}
            asm volatile("" ::: "memory");
            hs[uidx] = __hip_atomic_load(&xh[((size_t)b * 2 + ((t - 1) & 1)) * 256 + uidx],
                                         __ATOMIC_RELAXED, __HIP_MEMORY_SCOPE_SYSTEM);
        }
        __syncthreads();   // syncA: kred + full hs visible; A/X prefetch drained free

        // ======== phase B: GEMV (all), KAN reduce (w<3), stage xs(t+1) ========
        {
            float hreg = hs[p * 64 + lane];
            float a0 = 0.f, a1 = 0.f, a2 = 0.f;
#pragma unroll
            for (int uu = 0; uu < 64; ++uu) {
                float hu = rdlane(hreg, uu);
                a0 = fmaf(hu, Rf[0][uu], a0);
                a1 = fmaf(hu, Rf[1][uu], a1);
                a2 = fmaf(hu, Rf[2][uu], a2);
            }
            zred[w][lane][0] = a0;
            zred[w][lane][1] = a1;
            zred[w][lane][2] = a2;
        }
        if (w < 3) {                               // KAN reduce (kred ready at syncA)
            float v = kred[w * 256 + lane] + kred[w * 256 + 64 + lane]
                    + kred[w * 256 + 128 + lane] + kred[w * 256 + 192 + lane];
#pragma unroll
            for (int m = 32; m > 0; m >>= 1) v += __shfl_xor(v, m, 64);
            if (lane == 0) {
                so_l[w] = v;
                subs[w] = st2[w * 2] * v + st2[w * 2 + 1] * subs[w];
            }
        }
        if (xduty) xs[xi] = xv;                    // stage x(t+1) from register
        __syncthreads();   // syncB: zred + so_l + xs(t+1) visible

        // ======== phase C: gates + state update + EARLY per-wave publish ========
        if (pstate) {
            float z0 = az0, z1 = az1, z2 = az2;
#pragma unroll
            for (int q = 0; q < 4; ++q) {
                z0 += zred[w + q][lane][0];
                z1 += zred[w + q][lane][1];
                z2 += zred[w + q][lane][2];
            }
            float ig = sigm(z0);
            float fg = sigm(z1);
            c_reg = fg * c_reg + ig * tanh_fast(z2);
            float og = sigm(so_l[0] * aw0 + so_l[1] * aw1 + so_l[2] * aw2 + ab);
            float hn = og * tanh_fast(c_reg);
            hs[ui] = hn;
            hhist[tl][c] = hn;
            if (tl < TC - 1) {
                // write-through store of this wave's 64 h values...
                __hip_atomic_store(&xh[((size_t)b * 2 + (t & 1)) * 256 + ui], hn,
                                   __ATOMIC_RELAXED, __HIP_MEMORY_SCOPE_SYSTEM);
                // ...drain ONLY this wave's stores (A/X prefetch drained at syncA),
                // then publish this half's flag. Partner unblocked pre-barrier.
                asm volatile("s_waitcnt vmcnt(0)" ::: "memory");
                if (lane == 0)
                    __hip_atomic_store(&flags[(b * 2 + r) * 2 + (w >> 2)], t,
                                       __ATOMIC_RELAXED, __HIP_MEMORY_SCOPE_SYSTEM);
            } else {
                ws_h[b * 256 + ui] = hn;
                ws_c[b * 256 + ui] = c_reg;
            }
            az0 = an0; az1 = an1; az2 = an2;
        }
        __syncthreads();   // syncC: hs own-half + subs safe for next phase A
    }

    // ---- epilogue: bulk out-write from LDS history (coalesced, off serial path) ----
    for (int i = tid; i < TC * 128; i += 512) {
        int tl = i >> 7, cc = i & 127;
        out[((size_t)b * T_ + t0 + tl) * U_ + r * 128 + cc] = hhist[tl][cc];
    }
    if (tid < 3) ws_sub[b * 3 + tid] = subs[tid];
}

extern "C" void kernel_launch(void* const* d_in, const int* in_sizes, int n_in,
                              void* d_out, int out_size, void* d_ws, size_t ws_size,
                              hipStream_t stream) {
    const float* x    = (const float*)d_in[0];
    const float* Kmat = (const float*)d_in[1];
    const float* R    = (const float*)d_in[2];
    const float* bias = (const float*)d_in[3];
    const float* stk  = (const float*)d_in[4];
    const float* strk = (const float*)d_in[5];
    const float* aggw = (const float*)d_in[6];
    const float* aggb = (const float*)d_in[7];
    const float* kbw  = (const float*)d_in[8];
    const float* ksw  = (const float*)d_in[9];
    float* out = (float*)d_out;

    float* ws   = (float*)d_ws;
    float* A    = ws;                             // 6,291,456 floats (24 MB)
    float* wh   = A + (size_t)B_ * TC * TU;       // 32768
    float* wc   = wh + B_ * U_;                   // 32768
    float* wsub = wc + B_ * U_;                   // 384 (pad to 512)
    float* xh   = wsub + 512;                     // B*2*256 = 65536
    int*   flg  = (int*)(xh + (size_t)B_ * 2 * 256);  // 512 ints [B][2][2]

    k0_init<<<dim3(B_), dim3(256), 0, stream>>>(wh, wc, wsub, flg);
    for (int ci = 0; ci < NC; ++ci) {
        k1_gemm<<<dim3((B_ * TC) / 64, TU / 64), dim3(256), 0, stream>>>(x, Kmat, bias, A, ci * TC);
        k2_rec<<<dim3(2 * B_), dim3(512), 0, stream>>>(A, x, R, stk, strk, aggw, aggb, kbw, ksw,
                                                       out, wh, wc, wsub, xh, flg, ci * TC);
    }
}